// Round 20
// baseline (70.794 us; speedup 1.0000x reference)
//
#include <hip/hip_runtime.h>

// 2-layer tanh RNN, INP=6, HID=8, B=4096, T=512, + linear head to 1.
// R20 = R19 (48.5us) with EPW halved to 2 and grid doubled to 2048 blocks
// of 32 threads: 2 waves per SIMD. Per-wave code is identical (parity-
// interleaved 16-lane state, single-level ror gathers, pk dots, forced
// inline-asm ds_read pipeline); each wave's ~120cyc/step dependency stalls
// are filled by the OTHER wave's issue via hardware round-robin.
// Only the LDS layout changes: 2-element f4 interleave (slot = q*2+e),
// 192 B/body offsets.

#define INP 6
#define HID 8
#define TT  512
#define CH  64                // steps per chunk
#define NCH (TT/CH)           // 8 chunks
#define EPW 2                 // elements per wave
#define CHF (CH*INP)          // 384 floats per element-chunk
#define BUFF (EPW*CHF)        // 768 floats per LDS buffer (3072 B)

#define DPP_XOR1 0xB1   // quad_perm(1,0,3,2): lane ^ 1 (parity partner)
#define ROR2  0x122     // row_ror:2
#define ROR4  0x124
#define ROR6  0x126
#define ROR8  0x128
#define ROR10 0x12A
#define ROR12 0x12C
#define ROR14 0x12E

#define KSC 2.88539008177793f   // 2 / ln(2)

typedef float v2f __attribute__((ext_vector_type(2)));

template<int CTRL>
__device__ __forceinline__ float fdpp(float v) {
    return __int_as_float(__builtin_amdgcn_update_dpp(
        0, __float_as_int(v), CTRL, 0xF, 0xF, true));
}
template<int CTRL>
__device__ __forceinline__ int idpp(int v) {
    return __builtin_amdgcn_update_dpp(0, v, CTRL, 0xF, 0xF, true);
}

// tanh on PRE-SCALED input (z = 2/ln2 * raw): 1 - 2/(exp2(z)+1)
__device__ __forceinline__ float ftanhs(float z) {
    float e = __builtin_amdgcn_exp2f(z);
    return fmaf(-2.0f, __builtin_amdgcn_rcpf(e + 1.0f), 1.0f);
}

// async global->LDS, 16B per lane, LDS dst = uniform base + lane*16
__device__ __forceinline__ void gl2lds16(const float* g, float* l) {
    __builtin_amdgcn_global_load_lds(
        (const __attribute__((address_space(1))) void*)g,
        (__attribute__((address_space(3))) void*)l, 16, 0, 0);
}

#define WAITLGKM  asm volatile("s_waitcnt lgkmcnt(0)" ::: "memory")
#define WAITVM    asm volatile("s_waitcnt vmcnt(0)" ::: "memory")
#define SB        __builtin_amdgcn_sched_barrier(0)

// un-sinkable LDS read: ds_read_b64 into a v2f pair, compile-time offset
#define DSRO(dst, av, LIT) \
    asm volatile("ds_read_b64 %0, %1 offset:" LIT : "=v"(dst) : "v"(av));

// 12 reads for one 4-step body, first consumed timestep tt0 = 4*kb+1.
// 2-element interleave: float f of element el at byte 32*(f>>2)+16el+4*(f&3).
// av = chunkbase(+el*16) + 192*kb.
#define LDB_STD(B, av)            \
    DSRO(B[0],  av, "40")         \
    DSRO(B[1],  av, "64")         \
    DSRO(B[2],  av, "72")         \
    DSRO(B[3],  av, "96")         \
    DSRO(B[4],  av, "104")        \
    DSRO(B[5],  av, "128")        \
    DSRO(B[6],  av, "136")        \
    DSRO(B[7],  av, "160")        \
    DSRO(B[8],  av, "168")        \
    DSRO(B[9],  av, "192")        \
    DSRO(B[10], av, "200")        \
    DSRO(B[11], av, "224")

// split variant for body 15: last timestep = next chunk's x(0) from avn
#define LDB_SPLIT(B, av, avn)     \
    DSRO(B[0],  av,  "40")        \
    DSRO(B[1],  av,  "64")        \
    DSRO(B[2],  av,  "72")        \
    DSRO(B[3],  av,  "96")        \
    DSRO(B[4],  av,  "104")       \
    DSRO(B[5],  av,  "128")       \
    DSRO(B[6],  av,  "136")       \
    DSRO(B[7],  av,  "160")       \
    DSRO(B[8],  av,  "168")       \
    DSRO(B[9],  avn, "0")         \
    DSRO(B[10], avn, "8")         \
    DSRO(B[11], avn, "32")

// core fused step (R19-verbatim). Entry: v = (h1(t)|h2(t-1)) parity-
// interleaved. Exit: v = (h1(t+1)|h2(t)). ss on even lanes = head o(t-1),
// captured where u == (S+7)&7.
#define STEPC(S, X0, X1, X2)                                       \
  {                                                                \
    v2f G0, G1, G2, G3;                                            \
    G0.x = v;                                                      \
    G0.y = fdpp<ROR2>(v);                                          \
    G1.x = fdpp<ROR4>(v);                                          \
    G1.y = fdpp<ROR6>(v);                                          \
    G2.x = fdpp<ROR8>(v);                                          \
    G2.y = fdpp<ROR10>(v);                                         \
    G3.x = fdpp<ROR12>(v);                                         \
    G3.y = fdpp<ROR14>(v);                                         \
    v2f PA = __builtin_elementwise_fma(wxp0, X0, biasp);           \
    PA = __builtin_elementwise_fma(wxp1, X1, PA);                  \
    PA = __builtin_elementwise_fma(wxp2, X2, PA);                  \
    PA = __builtin_elementwise_fma(wmp0, G0, PA);                  \
    PA = __builtin_elementwise_fma(wmp1, G1, PA);                  \
    PA = __builtin_elementwise_fma(wmp2, G2, PA);                  \
    PA = __builtin_elementwise_fma(wmp3, G3, PA);                  \
    v2f PC = wsp0 * G0;                                            \
    PC = __builtin_elementwise_fma(wsp1, G1, PC);                  \
    PC = __builtin_elementwise_fma(wsp2, G2, PC);                  \
    PC = __builtin_elementwise_fma(wsp3, G3, PC);                  \
    float s  = PC.x + PC.y;                                        \
    float ss = fdpp<DPP_XOR1>(s);                                  \
    float pre = PA.x + PA.y;                                       \
    float tin = fmaf(upf, ss, pre);                                \
    v = ftanhs(tin);                                               \
    oreg = (u == (((S) + 7) & 7)) ? ss : oreg;                     \
  }

__global__ __launch_bounds__(32) void rnn_fused(
    const float* __restrict__ x,
    const float* __restrict__ Wih0, const float* __restrict__ Whh0,
    const float* __restrict__ bih0, const float* __restrict__ bhh0,
    const float* __restrict__ Wih1, const float* __restrict__ Whh1,
    const float* __restrict__ bih1, const float* __restrict__ bhh1,
    const float* __restrict__ Wout, const float* __restrict__ bout,
    float* __restrict__ out)
{
    __shared__ float lx[2 * BUFF];   // 6 KiB, double-buffered x chunks

    const int lane = threadIdx.x;        // 0..31 (one half-populated wave)
    const int p    = lane & 1;           // 0: h1 lane, 1: h2 lane
    const int u    = (lane >> 1) & 7;    // hidden unit owned by this lane
    const int el   = lane >> 4;          // element slot (0..1)
    const int ew0  = blockIdx.x * EPW;   // wave's first batch element

    // --- probe row_ror direction (lanes 0-15 suffice) ---
    const int lid16 = lane & 15;
    const int pr2 = idpp<ROR2>(lid16);
    const bool dplus = (pr2 == ((lid16 + 2) & 15));

    // per-lane weights (tanh-path PRE-SCALED by 2/ln2), paired over c:
    // gather c: state unit idx(c) = (u +- c) & 7, same parity.
    v2f wmp0, wmp1, wmp2, wmp3, wsp0, wsp1, wsp2, wsp3;
    {
        float wm[8], ws[8];
#pragma unroll
        for (int c = 0; c < 8; ++c) {
            int idx = dplus ? ((u + c) & 7) : ((u - c) & 7);
            wm[c] = KSC * (p ? Whh1[u * HID + idx] : Whh0[u * HID + idx]);
            ws[c] = p ? Wout[idx] : KSC * Wih1[u * HID + idx];
        }
        wmp0.x = wm[0]; wmp0.y = wm[1]; wmp1.x = wm[2]; wmp1.y = wm[3];
        wmp2.x = wm[4]; wmp2.y = wm[5]; wmp3.x = wm[6]; wmp3.y = wm[7];
        wsp0.x = ws[0]; wsp0.y = ws[1]; wsp1.x = ws[2]; wsp1.y = ws[3];
        wsp2.x = ws[4]; wsp2.y = ws[5]; wsp3.x = ws[6]; wsp3.y = ws[7];
    }
    v2f wxp0, wxp1, wxp2;
    wxp0.x = p ? 0.0f : KSC * Wih0[u * INP + 0];
    wxp0.y = p ? 0.0f : KSC * Wih0[u * INP + 1];
    wxp1.x = p ? 0.0f : KSC * Wih0[u * INP + 2];
    wxp1.y = p ? 0.0f : KSC * Wih0[u * INP + 3];
    wxp2.x = p ? 0.0f : KSC * Wih0[u * INP + 4];
    wxp2.y = p ? 0.0f : KSC * Wih0[u * INP + 5];
    const float bias = KSC * (p ? (bih1[u] + bhh1[u]) : (bih0[u] + bhh0[u]));
    v2f biasp; biasp.x = bias; biasp.y = 0.0f;
    const float upf  = p ? 1.0f : 0.0f;
    const float bo   = bout[0];

    const float* xw = x + (size_t)ew0 * (TT * INP);
    float* ob = out + (size_t)(ew0 + el) * TT;

    // stage chunk c1 (2 elements x 384 floats = 192 f4 slots) into buffer
    // pn; slot S = q*2 + e; 6 iters x 32 lanes; dst = base + lane*16B
    auto stage = [&](int c1, int pn) {
#pragma unroll
        for (int i = 0; i < 6; ++i) {
            const int e = lane & 1;
            const int q = i * 16 + (lane >> 1);
            const float* src = xw + (size_t)e * (TT * INP) + c1 * CHF + q * 4;
            gl2lds16(src, &lx[pn * BUFF + i * 128]);
        }
    };

    // 32-bit LDS byte base for asm ds_read addressing
    const unsigned lb =
        (unsigned)(size_t)((__attribute__((address_space(3))) char*)(char*)lx);
    const unsigned elo = lb + (unsigned)(el * 16);

    float v = 0.0f;           // even lanes: h1[u](t); odd lanes: h2[u](t-1)
    float oreg = 0.0f;        // even lanes: head outputs, slot = u
    v2f XA[12], XB[12];       // 4-step x blocks, ping-pong, FORCED registers

    // ---- prologue: stage chunk 0; h1(0); issue body-0 reads ----
    stage(0, 0);
    WAITVM; SB;
    {
        const float* rb = &lx[el * 4];
        v2f x00 = *reinterpret_cast<const v2f*>(rb);        // f0,f1
        v2f x01 = *reinterpret_cast<const v2f*>(rb + 2);    // f2,f3
        v2f x02 = *reinterpret_cast<const v2f*>(rb + 8);    // f4,f5
        unsigned av0 = elo;
        LDB_STD(XA, av0)
        SB;
        v2f a = __builtin_elementwise_fma(wxp0, x00, biasp);
        a = __builtin_elementwise_fma(wxp1, x01, a);
        a = __builtin_elementwise_fma(wxp2, x02, a);
        float t0v = ftanhs(a.x + a.y);
        v = p ? 0.0f : t0v;    // h2(-1) = 0
    }

    for (int c = 0; c < NCH; ++c) {
        const unsigned cb = elo + (unsigned)((c & 1) * 3072);
        const unsigned nb = elo + (unsigned)(((c + 1) & 1) * 3072);
        if (c < NCH - 1) stage(c + 1, (c + 1) & 1);   // ~64 steps of cover

        for (int m = 0; m < 7; ++m) {
            // body even (kb=2m): consume XA, issue XB for kb=2m+1
            WAITLGKM; SB;
            { unsigned av = cb + (unsigned)(192 * (2 * m + 1)); LDB_STD(XB, av) }
            SB;
            STEPC(0, XA[0], XA[1], XA[2])
            if ((c | m) && !p) ob[c * CH + m * 8 - 8 + u] = oreg + bo;
            STEPC(1, XA[3], XA[4], XA[5])
            STEPC(2, XA[6], XA[7], XA[8])
            STEPC(3, XA[9], XA[10], XA[11])
            // body odd (kb=2m+1): consume XB, issue XA for kb=2m+2
            WAITLGKM; SB;
            { unsigned av = cb + (unsigned)(192 * (2 * m + 2)); LDB_STD(XA, av) }
            SB;
            STEPC(4, XB[0], XB[1], XB[2])
            STEPC(5, XB[3], XB[4], XB[5])
            STEPC(6, XB[6], XB[7], XB[8])
            STEPC(7, XB[9], XB[10], XB[11])
        }
        // body 14 (kb=14): consume XA, issue XB for kb=15 (split: last
        // timestep from the next chunk's buffer -> drain staging first)
        WAITLGKM; SB;
        WAITVM; SB;
        { unsigned av = cb + (unsigned)(192 * 15); LDB_SPLIT(XB, av, nb) }
        SB;
        STEPC(0, XA[0], XA[1], XA[2])
        if (!p) ob[c * CH + 48 + u] = oreg + bo;      // window sb=6
        STEPC(1, XA[3], XA[4], XA[5])
        STEPC(2, XA[6], XA[7], XA[8])
        STEPC(3, XA[9], XA[10], XA[11])
        // body 15 (kb=15): consume XB, issue XA for next chunk's body 0
        WAITLGKM; SB;
        if (c < NCH - 1) { LDB_STD(XA, nb) }
        SB;
        STEPC(4, XB[0], XB[1], XB[2])
        STEPC(5, XB[3], XB[4], XB[5])
        STEPC(6, XB[6], XB[7], XB[8])
        STEPC(7, XB[9], XB[10], XB[11])
        // (c==7: XB[9..11] stale -> only h1(512), never used)
    }

    // ---- epilogue: head for t = 511 (slot 7), then store final block ----
    {
        v2f G0, G1, G2, G3;
        G0.x = v;
        G0.y = fdpp<ROR2>(v);
        G1.x = fdpp<ROR4>(v);
        G1.y = fdpp<ROR6>(v);
        G2.x = fdpp<ROR8>(v);
        G2.y = fdpp<ROR10>(v);
        G3.x = fdpp<ROR12>(v);
        G3.y = fdpp<ROR14>(v);
        v2f PC = wsp0 * G0;
        PC = __builtin_elementwise_fma(wsp1, G1, PC);
        PC = __builtin_elementwise_fma(wsp2, G2, PC);
        PC = __builtin_elementwise_fma(wsp3, G3, PC);
        float s  = PC.x + PC.y;      // odd lanes: Wout . h2(511)
        float ss = fdpp<DPP_XOR1>(s);
        oreg = (u == 7) ? ss : oreg;
        if (!p) ob[TT - 8 + u] = oreg + bo;
    }
}

extern "C" void kernel_launch(void* const* d_in, const int* in_sizes, int n_in,
                              void* d_out, int out_size, void* d_ws, size_t ws_size,
                              hipStream_t stream) {
    const float* x    = (const float*)d_in[0];
    const float* Wih0 = (const float*)d_in[1];
    const float* Whh0 = (const float*)d_in[2];
    const float* bih0 = (const float*)d_in[3];
    const float* bhh0 = (const float*)d_in[4];
    const float* Wih1 = (const float*)d_in[5];
    const float* Whh1 = (const float*)d_in[6];
    const float* bih1 = (const float*)d_in[7];
    const float* bhh1 = (const float*)d_in[8];
    const float* Wout = (const float*)d_in[9];
    const float* bout = (const float*)d_in[10];
    float* out = (float*)d_out;
    (void)d_ws; (void)ws_size; (void)in_sizes; (void)n_in; (void)out_size;

    // 4096 elements / 2 per wave = 2048 blocks of 32 threads (one wave
    // each, lanes 0-31) -> 2 waves per SIMD: hardware stall-filling.
    rnn_fused<<<2048, 32, 0, stream>>>(x, Wih0, Whh0, bih0, bhh0,
                                       Wih1, Whh1, bih1, bhh1,
                                       Wout, bout, out);
}

// Round 21
// 48.832 us; speedup vs baseline: 1.4497x; 1.4497x over previous
//
#include <hip/hip_runtime.h>

// 2-layer tanh RNN, INP=6, HID=8, B=4096, T=512, + linear head to 1.
// R21 = R19 (best 48.5us) with tanh switched to the odd Pade(7,6) form:
// removes one transcendental (exp2) from the serial recurrence chain,
// trading it for chain-PARALLEL Horner polynomials + one rcp + med3 clamp.
// (R15 tested Pade on the pre-asm-pipeline base where issue was saturated;
// on this base VALUBusy=47% has slack and the exp's exposed latency is the
// target.) Weights revert to RAW (no 2/ln2 prescale). All else R19-verbatim:
// parity-interleaved 16-lane state, single-level ror gathers (direction
// probed), pk-paired dots, half-local sidecar + XOR1 scalar ship, forced
// inline-asm ds_read x pipeline, chunked global_load_lds staging.

#define INP 6
#define HID 8
#define TT  512
#define CH  64                // steps per chunk
#define NCH (TT/CH)           // 8 chunks
#define EPW 4                 // elements per wave
#define CHF (CH*INP)          // 384 floats per element-chunk
#define BUFF (EPW*CHF)        // 1536 floats per LDS buffer (6144 B)

#define DPP_XOR1 0xB1   // quad_perm(1,0,3,2): lane ^ 1 (parity partner)
#define ROR2  0x122     // row_ror:2
#define ROR4  0x124
#define ROR6  0x126
#define ROR8  0x128
#define ROR10 0x12A
#define ROR12 0x12C
#define ROR14 0x12E

typedef float v2f __attribute__((ext_vector_type(2)));

template<int CTRL>
__device__ __forceinline__ float fdpp(float v) {
    return __int_as_float(__builtin_amdgcn_update_dpp(
        0, __float_as_int(v), CTRL, 0xF, 0xF, true));
}
template<int CTRL>
__device__ __forceinline__ int idpp(int v) {
    return __builtin_amdgcn_update_dpp(0, v, CTRL, 0xF, 0xF, true);
}

#if defined(__HIP_DEVICE_COMPILE__) && __has_builtin(__builtin_amdgcn_fmed3f)
  #define CLAMP1(t) __builtin_amdgcn_fmed3f((t), -1.0f, 1.0f)
#else
  #define CLAMP1(t) fminf(1.0f, fmaxf(-1.0f, (t)))
#endif

// tanh via odd Pade(7,6): z*(135135+17325z^2+378z^4+z^6) /
//                           (135135+62370z^2+3150z^4+28z^6), clamped.
// One transcendental (rcp) in the chain; P,Q Horners run in parallel on
// the FMA pipe. |err| <= ~9e-5; overshoot for z>5 is >= 1 -> clamp exact.
__device__ __forceinline__ float ftanh_pade(float z) {
    float z2 = z * z;
    float P = fmaf(fmaf(z2 + 378.0f, z2, 17325.0f), z2, 135135.0f);
    float Q = fmaf(fmaf(fmaf(28.0f, z2, 3150.0f), z2, 62370.0f), z2, 135135.0f);
    float t = (z * P) * __builtin_amdgcn_rcpf(Q);
    return CLAMP1(t);
}

// async global->LDS, 16B per lane, LDS dst = uniform base + lane*16
__device__ __forceinline__ void gl2lds16(const float* g, float* l) {
    __builtin_amdgcn_global_load_lds(
        (const __attribute__((address_space(1))) void*)g,
        (__attribute__((address_space(3))) void*)l, 16, 0, 0);
}

#define WAITLGKM  asm volatile("s_waitcnt lgkmcnt(0)" ::: "memory")
#define WAITVM    asm volatile("s_waitcnt vmcnt(0)" ::: "memory")
#define SB        __builtin_amdgcn_sched_barrier(0)

// un-sinkable LDS read: ds_read_b64 into a v2f pair, compile-time offset
#define DSRO(dst, av, LIT) \
    asm volatile("ds_read_b64 %0, %1 offset:" LIT : "=v"(dst) : "v"(av));

// 12 reads for one 4-step body, first consumed timestep tt0 = 4*kb+1.
// Offsets from av = chunkbase + 384*kb (bytes); interleaved layout:
// float f of element el at byte 64*(f>>2)+16el+4*(f&3).
#define LDB_STD(B, av)            \
    DSRO(B[0],  av, "72")         \
    DSRO(B[1],  av, "128")        \
    DSRO(B[2],  av, "136")        \
    DSRO(B[3],  av, "192")        \
    DSRO(B[4],  av, "200")        \
    DSRO(B[5],  av, "256")        \
    DSRO(B[6],  av, "264")        \
    DSRO(B[7],  av, "320")        \
    DSRO(B[8],  av, "328")        \
    DSRO(B[9],  av, "384")        \
    DSRO(B[10], av, "392")        \
    DSRO(B[11], av, "448")

// split variant for body 15: last timestep = next chunk's x(0) from avn
#define LDB_SPLIT(B, av, avn)     \
    DSRO(B[0],  av,  "72")        \
    DSRO(B[1],  av,  "128")       \
    DSRO(B[2],  av,  "136")       \
    DSRO(B[3],  av,  "192")       \
    DSRO(B[4],  av,  "200")       \
    DSRO(B[5],  av,  "256")       \
    DSRO(B[6],  av,  "264")       \
    DSRO(B[7],  av,  "320")       \
    DSRO(B[8],  av,  "328")       \
    DSRO(B[9],  avn, "0")         \
    DSRO(B[10], avn, "8")         \
    DSRO(B[11], avn, "64")

// core fused step. Entry: v = (h1(t)|h2(t-1)) parity-interleaved.
// Exit: v = (h1(t+1)|h2(t)). ss on even lanes = head o(t-1), captured
// where u == (S+7)&7.
#define STEPC(S, X0, X1, X2)                                       \
  {                                                                \
    v2f G0, G1, G2, G3;                                            \
    G0.x = v;                                                      \
    G0.y = fdpp<ROR2>(v);                                          \
    G1.x = fdpp<ROR4>(v);                                          \
    G1.y = fdpp<ROR6>(v);                                          \
    G2.x = fdpp<ROR8>(v);                                          \
    G2.y = fdpp<ROR10>(v);                                         \
    G3.x = fdpp<ROR12>(v);                                         \
    G3.y = fdpp<ROR14>(v);                                         \
    v2f PA = __builtin_elementwise_fma(wxp0, X0, biasp);           \
    PA = __builtin_elementwise_fma(wxp1, X1, PA);                  \
    PA = __builtin_elementwise_fma(wxp2, X2, PA);                  \
    PA = __builtin_elementwise_fma(wmp0, G0, PA);                  \
    PA = __builtin_elementwise_fma(wmp1, G1, PA);                  \
    PA = __builtin_elementwise_fma(wmp2, G2, PA);                  \
    PA = __builtin_elementwise_fma(wmp3, G3, PA);                  \
    v2f PC = wsp0 * G0;                                            \
    PC = __builtin_elementwise_fma(wsp1, G1, PC);                  \
    PC = __builtin_elementwise_fma(wsp2, G2, PC);                  \
    PC = __builtin_elementwise_fma(wsp3, G3, PC);                  \
    float s  = PC.x + PC.y;                                        \
    float ss = fdpp<DPP_XOR1>(s);                                  \
    float pre = PA.x + PA.y;                                       \
    float tin = fmaf(upf, ss, pre);                                \
    v = ftanh_pade(tin);                                           \
    oreg = (u == (((S) + 7) & 7)) ? ss : oreg;                     \
  }

__global__ __launch_bounds__(64) void rnn_fused(
    const float* __restrict__ x,
    const float* __restrict__ Wih0, const float* __restrict__ Whh0,
    const float* __restrict__ bih0, const float* __restrict__ bhh0,
    const float* __restrict__ Wih1, const float* __restrict__ Whh1,
    const float* __restrict__ bih1, const float* __restrict__ bhh1,
    const float* __restrict__ Wout, const float* __restrict__ bout,
    float* __restrict__ out)
{
    __shared__ float lx[2 * BUFF];   // 12 KiB, double-buffered x chunks

    const int lane = threadIdx.x;        // 0..63
    const int p    = lane & 1;           // 0: h1 lane, 1: h2 lane
    const int u    = (lane >> 1) & 7;    // hidden unit owned by this lane
    const int el   = lane >> 4;          // element slot (0..3)
    const int ew0  = blockIdx.x * EPW;   // wave's first batch element

    // --- probe row_ror direction ---
    const int lid16 = lane & 15;
    const int pr2 = idpp<ROR2>(lid16);
    const bool dplus = (pr2 == ((lid16 + 2) & 15));

    // per-lane weights (RAW, no prescale), paired over rotation count c:
    // gather c: state unit idx(c) = (u +- c) & 7, same parity.
    //  main (wmp): even Whh0[u][idx], odd Whh1[u][idx]
    //  side (wsp): even Wih1[u][idx] (ships to odd partner),
    //              odd Wout[idx] (head, ships to even partner)
    v2f wmp0, wmp1, wmp2, wmp3, wsp0, wsp1, wsp2, wsp3;
    {
        float wm[8], ws[8];
#pragma unroll
        for (int c = 0; c < 8; ++c) {
            int idx = dplus ? ((u + c) & 7) : ((u - c) & 7);
            wm[c] = p ? Whh1[u * HID + idx] : Whh0[u * HID + idx];
            ws[c] = p ? Wout[idx] : Wih1[u * HID + idx];
        }
        wmp0.x = wm[0]; wmp0.y = wm[1]; wmp1.x = wm[2]; wmp1.y = wm[3];
        wmp2.x = wm[4]; wmp2.y = wm[5]; wmp3.x = wm[6]; wmp3.y = wm[7];
        wsp0.x = ws[0]; wsp0.y = ws[1]; wsp1.x = ws[2]; wsp1.y = ws[3];
        wsp2.x = ws[4]; wsp2.y = ws[5]; wsp3.x = ws[6]; wsp3.y = ws[7];
    }
    v2f wxp0, wxp1, wxp2;
    wxp0.x = p ? 0.0f : Wih0[u * INP + 0];
    wxp0.y = p ? 0.0f : Wih0[u * INP + 1];
    wxp1.x = p ? 0.0f : Wih0[u * INP + 2];
    wxp1.y = p ? 0.0f : Wih0[u * INP + 3];
    wxp2.x = p ? 0.0f : Wih0[u * INP + 4];
    wxp2.y = p ? 0.0f : Wih0[u * INP + 5];
    const float bias = p ? (bih1[u] + bhh1[u]) : (bih0[u] + bhh0[u]);
    v2f biasp; biasp.x = bias; biasp.y = 0.0f;
    const float upf  = p ? 1.0f : 0.0f;
    const float bo   = bout[0];

    const float* xw = x + (size_t)ew0 * (TT * INP);
    float* ob = out + (size_t)(ew0 + el) * TT;

    // stage chunk c1 (4 elements x 384 floats) into buffer pn, interleaved:
    // LDS f4 slot S = q*4 + e
    auto stage = [&](int c1, int pn) {
#pragma unroll
        for (int i = 0; i < 6; ++i) {
            const int e = lane & 3;
            const int q = i * 16 + (lane >> 2);
            const float* src = xw + (size_t)e * (TT * INP) + c1 * CHF + q * 4;
            gl2lds16(src, &lx[pn * BUFF + i * 256]);
        }
    };

    // 32-bit LDS byte base for asm ds_read addressing
    const unsigned lb =
        (unsigned)(size_t)((__attribute__((address_space(3))) char*)(char*)lx);
    const unsigned elo = lb + (unsigned)(el * 16);

    float v = 0.0f;           // even lanes: h1[u](t); odd lanes: h2[u](t-1)
    float oreg = 0.0f;        // even lanes: head outputs, slot = u
    v2f XA[12], XB[12];       // 4-step x blocks, ping-pong, FORCED registers

    // ---- prologue: stage chunk 0; h1(0); issue body-0 reads ----
    stage(0, 0);
    WAITVM; SB;
    {
        const float* rb = &lx[el * 4];
        v2f x00 = *reinterpret_cast<const v2f*>(rb);
        v2f x01 = *reinterpret_cast<const v2f*>(rb + 2);
        v2f x02 = *reinterpret_cast<const v2f*>(rb + 16);
        unsigned av0 = elo;
        LDB_STD(XA, av0)
        SB;
        v2f a = __builtin_elementwise_fma(wxp0, x00, biasp);
        a = __builtin_elementwise_fma(wxp1, x01, a);
        a = __builtin_elementwise_fma(wxp2, x02, a);
        float t0v = ftanh_pade(a.x + a.y);
        v = p ? 0.0f : t0v;    // h2(-1) = 0
    }

    for (int c = 0; c < NCH; ++c) {
        const unsigned cb = elo + (unsigned)((c & 1) * 6144);
        const unsigned nb = elo + (unsigned)(((c + 1) & 1) * 6144);
        if (c < NCH - 1) stage(c + 1, (c + 1) & 1);   // ~64 steps of cover

        for (int m = 0; m < 7; ++m) {
            // body even (kb=2m): consume XA, issue XB for kb=2m+1
            WAITLGKM; SB;
            { unsigned av = cb + (unsigned)(384 * (2 * m + 1)); LDB_STD(XB, av) }
            SB;
            STEPC(0, XA[0], XA[1], XA[2])
            if ((c | m) && !p) ob[c * CH + m * 8 - 8 + u] = oreg + bo;
            STEPC(1, XA[3], XA[4], XA[5])
            STEPC(2, XA[6], XA[7], XA[8])
            STEPC(3, XA[9], XA[10], XA[11])
            // body odd (kb=2m+1): consume XB, issue XA for kb=2m+2
            WAITLGKM; SB;
            { unsigned av = cb + (unsigned)(384 * (2 * m + 2)); LDB_STD(XA, av) }
            SB;
            STEPC(4, XB[0], XB[1], XB[2])
            STEPC(5, XB[3], XB[4], XB[5])
            STEPC(6, XB[6], XB[7], XB[8])
            STEPC(7, XB[9], XB[10], XB[11])
        }
        // body 14 (kb=14): consume XA, issue XB for kb=15 (split: last
        // timestep from the next chunk's buffer -> drain staging first)
        WAITLGKM; SB;
        WAITVM; SB;
        { unsigned av = cb + (unsigned)(384 * 15); LDB_SPLIT(XB, av, nb) }
        SB;
        STEPC(0, XA[0], XA[1], XA[2])
        if (!p) ob[c * CH + 48 + u] = oreg + bo;      // window sb=6
        STEPC(1, XA[3], XA[4], XA[5])
        STEPC(2, XA[6], XA[7], XA[8])
        STEPC(3, XA[9], XA[10], XA[11])
        // body 15 (kb=15): consume XB, issue XA for next chunk's body 0
        WAITLGKM; SB;
        if (c < NCH - 1) { LDB_STD(XA, nb) }
        SB;
        STEPC(4, XB[0], XB[1], XB[2])
        STEPC(5, XB[3], XB[4], XB[5])
        STEPC(6, XB[6], XB[7], XB[8])
        STEPC(7, XB[9], XB[10], XB[11])
        // (c==7: XB[9..11] stale -> only h1(512), never used)
    }

    // ---- epilogue: head for t = 511 (slot 7), then store final block ----
    {
        v2f G0, G1, G2, G3;
        G0.x = v;
        G0.y = fdpp<ROR2>(v);
        G1.x = fdpp<ROR4>(v);
        G1.y = fdpp<ROR6>(v);
        G2.x = fdpp<ROR8>(v);
        G2.y = fdpp<ROR10>(v);
        G3.x = fdpp<ROR12>(v);
        G3.y = fdpp<ROR14>(v);
        v2f PC = wsp0 * G0;
        PC = __builtin_elementwise_fma(wsp1, G1, PC);
        PC = __builtin_elementwise_fma(wsp2, G2, PC);
        PC = __builtin_elementwise_fma(wsp3, G3, PC);
        float s  = PC.x + PC.y;      // odd lanes: Wout . h2(511)
        float ss = fdpp<DPP_XOR1>(s);
        oreg = (u == 7) ? ss : oreg;
        if (!p) ob[TT - 8 + u] = oreg + bo;
    }
}

extern "C" void kernel_launch(void* const* d_in, const int* in_sizes, int n_in,
                              void* d_out, int out_size, void* d_ws, size_t ws_size,
                              hipStream_t stream) {
    const float* x    = (const float*)d_in[0];
    const float* Wih0 = (const float*)d_in[1];
    const float* Whh0 = (const float*)d_in[2];
    const float* bih0 = (const float*)d_in[3];
    const float* bhh0 = (const float*)d_in[4];
    const float* Wih1 = (const float*)d_in[5];
    const float* Whh1 = (const float*)d_in[6];
    const float* bih1 = (const float*)d_in[7];
    const float* bhh1 = (const float*)d_in[8];
    const float* Wout = (const float*)d_in[9];
    const float* bout = (const float*)d_in[10];
    float* out = (float*)d_out;
    (void)d_ws; (void)ws_size; (void)in_sizes; (void)n_in; (void)out_size;

    // 4096 elements / 4 per wave = 1024 single-wave blocks -> 1 wave/SIMD
    rnn_fused<<<1024, 64, 0, stream>>>(x, Wih0, Whh0, bih0, bhh0,
                                       Wih1, Whh1, bih1, bhh1,
                                       Wout, bout, out);
}